// Round 9
// baseline (202.244 us; speedup 1.0000x reference)
//
#include <hip/hip_runtime.h>
#include <stdint.h>

#define B  8
#define TE 2048
#define TD 256
#define H  128

// ---------- kernel 1: register-tiled GEMM (unchanged R6) ----------
// E written t-tiled k-paired: EgT[b][tb][k2=64][tl=64][2]  (tb = t>>6, tl = t&63,
// k = 2*k2+half); F row-major [b][j][k].
#define FMA4(acc, s, wv) \
  acc.x += (s)*(wv).x; acc.y += (s)*(wv).y; acc.z += (s)*(wv).z; acc.w += (s)*(wv).w

__global__ __launch_bounds__(256) void proj_kernel(
    const float* __restrict__ enc, const float* __restrict__ dec,
    const float* __restrict__ Wa,  const float* __restrict__ Ua,
    float* __restrict__ EgT, float* __restrict__ Fg) {
  __shared__ float Ls[16 * 132];
  const float C2 = 2.8853900817779268f;  // 2*log2(e):  exp(2x) = exp2(C2*x)
  int tid = threadIdx.x;
  int bid = blockIdx.x;
  bool isE = (bid < 1024);
  int rbase = (isE ? bid : bid - 1024) * 16;
  const float* in = isE ? enc : dec;
  const float* Mg = isE ? Wa : Ua;
  int hq = tid & 31, rq = tid >> 5;
  int h0 = hq * 4, r0 = rq * 2;
  const float* rowp = in + (size_t)(rbase + r0) * H;
  const float* wp = Mg + h0;
  float4 a0{0,0,0,0}, a1{0,0,0,0};
  #pragma unroll 2
  for (int kb = 0; kb < 32; ++kb) {
    float4 rv0 = *(const float4*)(rowp + kb * 4);
    float4 rv1 = *(const float4*)(rowp + H + kb * 4);
    float4 w0 = *(const float4*)(wp + (size_t)(4 * kb + 0) * H);
    float4 w1 = *(const float4*)(wp + (size_t)(4 * kb + 1) * H);
    float4 w2 = *(const float4*)(wp + (size_t)(4 * kb + 2) * H);
    float4 w3 = *(const float4*)(wp + (size_t)(4 * kb + 3) * H);
    FMA4(a0, rv0.x, w0); FMA4(a0, rv0.y, w1); FMA4(a0, rv0.z, w2); FMA4(a0, rv0.w, w3);
    FMA4(a1, rv1.x, w0); FMA4(a1, rv1.y, w1); FMA4(a1, rv1.z, w2); FMA4(a1, rv1.w, w3);
  }
  float4 e0, e1;
  e0.x = __builtin_amdgcn_exp2f(a0.x * C2); e0.y = __builtin_amdgcn_exp2f(a0.y * C2);
  e0.z = __builtin_amdgcn_exp2f(a0.z * C2); e0.w = __builtin_amdgcn_exp2f(a0.w * C2);
  e1.x = __builtin_amdgcn_exp2f(a1.x * C2); e1.y = __builtin_amdgcn_exp2f(a1.y * C2);
  e1.z = __builtin_amdgcn_exp2f(a1.z * C2); e1.w = __builtin_amdgcn_exp2f(a1.w * C2);
  if (isE) {
    // transpose through LDS, emit k-paired: dst[q*128 + tl*2 + half]
    *(float4*)&Ls[(r0 + 0) * 132 + h0] = e0;
    *(float4*)&Ls[(r0 + 1) * 132 + h0] = e1;
    __syncthreads();
    int b_e = rbase >> 11, t_in = rbase & 2047;
    int tb = t_in >> 6, toff = t_in & 63;  // 16-row chunk within the 64-t tile
    float* dst = EgT + (size_t)(b_e * 32 + tb) * 8192 + toff * 2;
    #pragma unroll
    for (int jj = 0; jj < 4; ++jj) {
      int idx = jj * 256 + tid;            // 1024 pairs
      int r = idx & 15, q = idx >> 4;      // r: row in chunk, q: k-pair 0..63
      float2 val{Ls[r * 132 + 2 * q], Ls[r * 132 + 2 * q + 1]};
      *(float2*)(dst + (size_t)q * 128 + r * 2) = val;  // 8B/lane, coalesced
    }
  } else {
    int b_f = rbase >> 8, j_in = rbase & 255;
    float* dst = Fg + ((size_t)(b_f * TD + j_in + r0)) * H + h0;
    *(float4*)(dst + 0 * H) = e0;
    *(float4*)(dst + 1 * H) = e1;
  }
}

// ---------- kernel 2: fused (R18: 2j x 512thr x 1024 blocks -> 8 waves/SIMD) ----------
// Occupancy test: 4 blocks/CU (32 waves) vs all prior configs' 16 waves. Phase-1
// micro-structure identical to R6 (b64 E, copy-free dbuf, original UNIT math).
__global__ __launch_bounds__(512, 8) void fused_kernel(
    const float* __restrict__ EgT, const float* __restrict__ Fg,
    const float* __restrict__ Va,  const float* __restrict__ enc,
    float* __restrict__ oute, float* __restrict__ outc) {
  __shared__ float S[2 * 2048];    // 16 KB: scores [j][t] -> e [j][t] -> c-partials
  __shared__ float red[16];
  int tid = threadIdx.x;
  int bid = blockIdx.x;
  int b = bid & 7, jt = bid >> 3;  // 1024 blocks; consecutive ids round-robin XCDs
  int j0 = jt * 2;
  int lane = tid & 63, w = tid >> 6;   // w in 0..7
  const float4* vp = (const float4*)Va;
  float V1 = 0.f;
  #pragma unroll
  for (int q = 0; q < 32; ++q) { float4 v = vp[q]; V1 += v.x + v.y + v.z + v.w; }

  // ---- phase 1: scores[j][t] = V1 - 2*sum_k v_k/(E[t,k]*F[j,k]+1) into LDS ----
  const float4* Fp = (const float4*)(Fg + (size_t)(b * TD + j0) * H);
  const float* Ep[4];
  #pragma unroll
  for (int it = 0; it < 4; ++it)       // t-tiles w, w+8, w+16, w+24; lane's pair base
    Ep[it] = EgT + (size_t)(b * 32 + w + 8 * it) * 8192 + lane * 2;
  float s[4][2];
  #pragma unroll
  for (int it = 0; it < 4; ++it) { s[it][0] = 0.f; s[it][1] = 0.f; }
  float2 eka[4], ekb[4];

  // 4 independent b64 loads (8 k), imm offsets; consumed one step later
#define LOADE2(dst, base, off)                                       \
  { const float* _p = (base) + (off);                                \
    dst[0] = *(const float2*)(_p);       dst[1] = *(const float2*)(_p + 128);  \
    dst[2] = *(const float2*)(_p + 256); dst[3] = *(const float2*)(_p + 384); }

  // exact original 2k-pair math (bit-identical scores to R6)
#define UNIT(acc, ekk, jj)                                                    \
  {                                                                           \
    float d0, d1, a = 0.f;                                                    \
    d0 = fmaf(ekk[0].x, f0[jj].x, 1.0f); d1 = fmaf(ekk[0].y, f0[jj].y, 1.0f); \
    a += (v0.x * d1 + v0.y * d0) * __builtin_amdgcn_rcpf(d0 * d1);            \
    d0 = fmaf(ekk[1].x, f0[jj].z, 1.0f); d1 = fmaf(ekk[1].y, f0[jj].w, 1.0f); \
    a += (v0.z * d1 + v0.w * d0) * __builtin_amdgcn_rcpf(d0 * d1);            \
    d0 = fmaf(ekk[2].x, f1[jj].x, 1.0f); d1 = fmaf(ekk[2].y, f1[jj].y, 1.0f); \
    a += (v1.x * d1 + v1.y * d0) * __builtin_amdgcn_rcpf(d0 * d1);            \
    d0 = fmaf(ekk[3].x, f1[jj].z, 1.0f); d1 = fmaf(ekk[3].y, f1[jj].w, 1.0f); \
    a += (v1.z * d1 + v1.w * d0) * __builtin_amdgcn_rcpf(d0 * d1);            \
    acc += a;                                                                 \
  }

  LOADE2(eka, Ep[0], 0);               // prologue: (kc=0, tile 0)
  for (int kc = 0; kc < 16; ++kc) {
    float4 f0[2], f1[2];               // block-uniform -> SGPR
    const float4* fpc = Fp + kc * 2;
    #pragma unroll
    for (int j = 0; j < 2; ++j) {
      f0[j] = fpc[j * 32];
      f1[j] = fpc[j * 32 + 1];
    }
    float4 v0 = vp[kc * 2], v1 = vp[kc * 2 + 1];
    // copy-free E ping-pong: tiles 0,2 in eka; 1,3 in ekb (within a kc)
    LOADE2(ekb, Ep[1], kc * 512);
    UNIT(s[0][0], eka, 0) UNIT(s[0][1], eka, 1)
    LOADE2(eka, Ep[2], kc * 512);
    UNIT(s[1][0], ekb, 0) UNIT(s[1][1], ekb, 1)
    LOADE2(ekb, Ep[3], kc * 512);
    UNIT(s[2][0], eka, 0) UNIT(s[2][1], eka, 1)
    LOADE2(eka, Ep[0], (kc + 1) * 512);  // kc=15: benign in-bounds over-read
    UNIT(s[3][0], ekb, 0) UNIT(s[3][1], ekb, 1)
  }
  #pragma unroll
  for (int it = 0; it < 4; ++it) {
    int t = (w + 8 * it) * 64 + lane;
    S[0 * 2048 + t] = V1 - 2.0f * s[it][0];  // bank = lane%32: 2-way (free)
    S[1 * 2048 + t] = V1 - 2.0f * s[it][1];
  }
  __syncthreads();

  // ---- phase 2: softmax per j-row (4 waves per j); e overwrites S in place ----
  int j = w >> 2, quarter = w & 3;
  int tb2 = quarter * 512 + lane;
  float x[8];
  #pragma unroll
  for (int q = 0; q < 8; ++q) x[q] = S[j * 2048 + tb2 + q * 64];
  float m = x[0];
  #pragma unroll
  for (int q = 1; q < 8; ++q) m = fmaxf(m, x[q]);
  #pragma unroll
  for (int off = 32; off > 0; off >>= 1) m = fmaxf(m, __shfl_xor(m, off));
  if (lane == 0) red[w] = m;
  __syncthreads();                             // also: all raw-S reads complete
  m = fmaxf(fmaxf(red[j * 4], red[j * 4 + 1]), fmaxf(red[j * 4 + 2], red[j * 4 + 3]));
  const float L2E = 1.4426950408889634f;
  float sum = 0.f;
  #pragma unroll
  for (int q = 0; q < 8; ++q) {
    x[q] = __builtin_amdgcn_exp2f((x[q] - m) * L2E);
    sum += x[q];
  }
  #pragma unroll
  for (int off = 32; off > 0; off >>= 1) sum += __shfl_xor(sum, off);
  if (lane == 0) red[8 + w] = sum;
  __syncthreads();
  float inv = 1.0f / ((red[8 + j * 4] + red[8 + j * 4 + 1]) +
                      (red[8 + j * 4 + 2] + red[8 + j * 4 + 3]));
  float* orow = oute + (size_t)(b * TD + j0 + j) * TE;
  #pragma unroll
  for (int q = 0; q < 8; ++q) {
    float e = x[q] * inv;
    int t = tb2 + q * 64;
    orow[t] = e;                               // coalesced 256 B/instr
    S[j * 2048 + t] = e;                       // in place: same slot it read
  }
  __syncthreads();

  // ---- phase 3: c[j][h] = sum_t e[j][t]*enc[t][h]; 16 slices x 128 t, pipelined ----
  int hq = tid & 31, slice = tid >> 5;         // h = hq*4; t in [slice*128, ...+128)
  const float* encp = enc + ((size_t)b * TE + slice * 128) * H + hq * 4;
  const float* Se = S + slice * 128;           // + j*2048 + t (b128 broadcast)
  float4 ac0{0,0,0,0}, ac1{0,0,0,0};
  float4 evA0, evA1, evA2, evA3, evB0, evB1, evB2, evB3;

#define LOADENC(d0, d1, d2, d3, t0)                         \
  d0 = *(const float4*)(encp + (size_t)(t0 + 0) * H);       \
  d1 = *(const float4*)(encp + (size_t)(t0 + 1) * H);       \
  d2 = *(const float4*)(encp + (size_t)(t0 + 2) * H);       \
  d3 = *(const float4*)(encp + (size_t)(t0 + 3) * H);

#define GROUP(t0, ex, ey, ez, ew)                                            \
  {                                                                          \
    float4 E0 = *(const float4*)&Se[0 * 2048 + (t0)];                        \
    float4 E1 = *(const float4*)&Se[1 * 2048 + (t0)];                        \
    FMA4(ac0, E0.x, ex); FMA4(ac0, E0.y, ey); FMA4(ac0, E0.z, ez); FMA4(ac0, E0.w, ew); \
    FMA4(ac1, E1.x, ex); FMA4(ac1, E1.y, ey); FMA4(ac1, E1.z, ez); FMA4(ac1, E1.w, ew); \
  }

  LOADENC(evA0, evA1, evA2, evA3, 0);
  #pragma unroll
  for (int tb = 0; tb < 128; tb += 8) {
    LOADENC(evB0, evB1, evB2, evB3, tb + 4);
    GROUP(tb, evA0, evA1, evA2, evA3);
    if (tb < 120) { LOADENC(evA0, evA1, evA2, evA3, tb + 8); }
    GROUP(tb + 4, evB0, evB1, evB2, evB3);
  }
  __syncthreads();                             // all e-reads done; reuse S for partials
  if (slice < 8) {                             // wave-uniform (waves 0-3)
    float* dst = &S[slice * 256 + hq * 4];
    *(float4*)(dst + 0)   = ac0;               // j=0 at +0..127
    *(float4*)(dst + 128) = ac1;               // j=1 at +128..255
  }
  __syncthreads();
  if (slice >= 8) {                            // waves 4-7: read-modify-add
    float* dst = &S[(slice - 8) * 256 + hq * 4];
    #define RMW(OFF, AC) { float4 p = *(float4*)(dst + OFF); \
      p.x += AC.x; p.y += AC.y; p.z += AC.z; p.w += AC.w; \
      *(float4*)(dst + OFF) = p; }
    RMW(0, ac0) RMW(128, ac1)
    #undef RMW
  }
  __syncthreads();
  if (tid < 256) {                             // waves 0-3, half active
    float r = 0.f;
    #pragma unroll
    for (int sl = 0; sl < 8; ++sl) r += S[sl * 256 + tid];   // stride-1, conflict-free
    outc[(size_t)(b * TD + j0 + (tid >> 7)) * H + (tid & 127)] = r;
  }
}

extern "C" void kernel_launch(void* const* d_in, const int* in_sizes, int n_in,
                              void* d_out, int out_size, void* d_ws, size_t ws_size,
                              hipStream_t stream) {
  (void)in_sizes; (void)n_in; (void)out_size; (void)ws_size;
  const float* enc = (const float*)d_in[0];
  const float* dec = (const float*)d_in[1];
  const float* Wa  = (const float*)d_in[2];
  const float* Ua  = (const float*)d_in[3];
  const float* Va  = (const float*)d_in[4];

  float* ws  = (float*)d_ws;
  float* EgT = ws;                                   // 8 MB  E tiled [b][tb][k2][tl][2]
  float* Fg  = EgT + (size_t)B * TE * H;             // 1 MB  F [b][j][k]
  float* outc = (float*)d_out;                       // c [B,TD,H] fp32
  float* oute = outc + (size_t)B * TD * H;           // e [B,TD,TE] fp32

  proj_kernel<<<dim3(1152), 256, 0, stream>>>(enc, dec, Wa, Ua, EgT, Fg);
  fused_kernel<<<dim3(1024), 512, 0, stream>>>(EgT, Fg, Va, enc, oute, outc);
}